// Round 9
// baseline (735.024 us; speedup 1.0000x reference)
//
#include <hip/hip_runtime.h>

#define KK 12
#define LL 4096
#define DD 128
#define NN 16
#define RR 8
#define NC 128             // chunks (one per block)
#define LC 32              // chunk length = l-tile per block
#define XST 140            // x-tile / ybuf LDS stride (12*l mod 32 -> 4-way GEMM reads)
#define SDST 44            // x_dbl LDS row stride (floats)
#define XDBL_TILE (LC * SDST)   // 1408 floats per (k,chunk) tile

__device__ __forceinline__ int pos_of(int k, int l) {
    int o = k >> 1;
    int le = (k & 1) ? (4095 - l) : l;
    int t1 = le >> 8, t2 = (le >> 4) & 15, t3 = le & 15;
    switch (o) {
        case 0:  return (t1 << 8) | (t2 << 4) | t3;
        case 1:  return (t1 << 8) | (t3 << 4) | t2;
        case 2:  return (t3 << 8) | (t2 << 4) | t1;
        case 3:  return (t2 << 8) | (t3 << 4) | t1;
        case 4:  return (t2 << 8) | (t1 << 4) | t3;
        default: return (t3 << 8) | (t1 << 4) | t2;
    }
}

// Inverse of the restore permutation: given k and jb (spatial index of the
// y slot), return p such that out[(p<<7)|dd] consumes y(k, d, l) with
// jb = (d<<5)|(l>>7), dd = l&127.  (Exact inverse of K4's gather.)
__device__ __forceinline__ int inv_pos(int k, int jb) {
    int j1 = jb >> 8, j2 = (jb >> 4) & 15, j3 = jb & 15;
    int a1, a2, a3;
    switch (k >> 1) {
        case 0:  a1 = j1; a2 = j2; a3 = j3; break;
        case 1:  a1 = j1; a3 = j2; a2 = j3; break;
        case 2:  a3 = j1; a2 = j2; a1 = j3; break;
        case 3:  a3 = j1; a1 = j2; a2 = j3; break;
        case 4:  a2 = j1; a1 = j2; a3 = j3; break;
        default: a2 = j1; a3 = j2; a1 = j3; break;
    }
    if (k & 1) { a1 = 15 - a1; a2 = 15 - a2; a3 = 15 - a3; }
    return (a1 << 8) | (a2 << 4) | a3;
}

__device__ __forceinline__ float delta_row_z(const float* sdbl, int l,
                                             float4 w0, float4 w1, float bz) {
    const float4* dr = (const float4*)(sdbl + l * SDST);
    float4 r0 = dr[0], r1 = dr[1];
    return bz + w0.x * r0.x + w0.y * r0.y + w0.z * r0.z + w0.w * r0.w
              + w1.x * r1.x + w1.y * r1.y + w1.z * r1.z + w1.w * r1.w;
}

__device__ __forceinline__ bool load_A8(const float* __restrict__ A_logs,
                                        int k, int d, int n0, float* A8, float& A0) {
    const float4* ap = (const float4*)(A_logs + ((size_t)(k * DD + d) * NN + n0));
    float4 a0 = ap[0], a1 = ap[1];
    A8[0] = -__expf(a0.x); A8[1] = -__expf(a0.y);
    A8[2] = -__expf(a0.z); A8[3] = -__expf(a0.w);
    A8[4] = -__expf(a1.x); A8[5] = -__expf(a1.y);
    A8[6] = -__expf(a1.z); A8[7] = -__expf(a1.w);
    A0 = -__expf(A_logs[(size_t)(k * DD + d) * NN]);
    bool s = true;
    #pragma unroll
    for (int j = 0; j < 8; j++) {
        float m = (float)(n0 + j + 1);
        s = s && (fabsf(A8[j] - m * A0) <= 1e-4f * m * fabsf(A0));
    }
    return s;
}

// e[j] = q^(n0+j+1) with q = exp(v*A0) (structured), else exp(v*A8[j])
template<bool S>
__device__ __forceinline__ void e8_from(float v, float A0, const float* A8,
                                        int half, float* e) {
    if (S) {
        float q = __expf(v * A0);
        float q2 = q * q, q4 = q2 * q2, q8 = q4 * q4;
        e[0] = half ? q8 * q : q;
        #pragma unroll
        for (int j = 1; j < 8; j++) e[j] = e[j - 1] * q;
    } else {
        #pragma unroll
        for (int j = 0; j < 8; j++) e[j] = __expf(v * A8[j]);
    }
}

// ---------------------------------------------------------------------------
// K0: init out = mb (harness poisons d_out before every launch).
// ---------------------------------------------------------------------------
__global__ __launch_bounds__(256) void k0_init(
    float* __restrict__ out, const float* __restrict__ mb)
{
    int idx = blockIdx.x * 256 + threadIdx.x;
    float b = mb[0];
    ((float4*)out)[idx] = make_float4(b, b, b, b);
}

// ---------------------------------------------------------------------------
// K1 scan body. Thread = (d, n-half). u from xs[l][d]; y written back into
// the same LDS word (column-exclusive per pair, intra-wave -> race-free).
// ---------------------------------------------------------------------------
template<bool S>
__device__ __forceinline__ void scanA_body(
    float* xs, const float* sdbl, int k, int c,
    int d, int half, int n0, const float* A8, float A0,
    float4 w0, float4 w1, float bz, float Dval,
    float* __restrict__ S_g, float* __restrict__ dtsum)
{
    float h[8] = {0, 0, 0, 0, 0, 0, 0, 0};
    float dsum = 0.0f;

    #pragma unroll 4
    for (int i = 0; i < LC; i++) {
        float z = delta_row_z(sdbl, i, w0, w1, bz);
        float E = __expf(-fabsf(z));
        float dt = fmaxf(z, 0.0f) + __logf(1.0f + E);
        float u = xs[i * XST + d];
        dsum += dt;
        float tu = dt * u;
        float e[8];
        e8_from<S>(dt, A0, A8, half, e);
        const float4* bp = (const float4*)(&sdbl[i * SDST + 8 + n0]);
        float4 b0 = bp[0], b1 = bp[1];
        const float4* cp = (const float4*)(&sdbl[i * SDST + 24 + n0]);
        float4 c0 = cp[0], c1 = cp[1];
        h[0] = e[0] * h[0] + tu * b0.x;  h[1] = e[1] * h[1] + tu * b0.y;
        h[2] = e[2] * h[2] + tu * b0.z;  h[3] = e[3] * h[3] + tu * b0.w;
        h[4] = e[4] * h[4] + tu * b1.x;  h[5] = e[5] * h[5] + tu * b1.y;
        h[6] = e[6] * h[6] + tu * b1.z;  h[7] = e[7] * h[7] + tu * b1.w;
        float yp = h[0] * c0.x + h[1] * c0.y + h[2] * c0.z + h[3] * c0.w
                 + h[4] * c1.x + h[5] * c1.y + h[6] * c1.z + h[7] * c1.w;
        float yv = yp + __shfl_xor(yp, 1) + Dval * u;
        if (!half) xs[i * XST + d] = yv;
    }

    float4* sp = (float4*)(S_g + (((size_t)(k * NC + c) * DD + d) * NN + n0));
    sp[0] = make_float4(h[0], h[1], h[2], h[3]);
    sp[1] = make_float4(h[4], h[5], h[6], h[7]);
    if (!half) dtsum[(k * NC + c) * DD + d] = dsum;
}

// ---------------------------------------------------------------------------
// K1: proj GEMM + phase A local scan + atomic merge into out.
// Block = (k, 32-l chunk), 256 threads. LDS ~23 KB -> 6 blocks/CU.
// ---------------------------------------------------------------------------
__global__ __launch_bounds__(256, 4) void k1_proj_scanA(
    const float* __restrict__ x, const float* __restrict__ Wp,
    const float* __restrict__ Wdt, const float* __restrict__ bias,
    const float* __restrict__ A_logs, const float* __restrict__ Ds,
    const float* __restrict__ mw,
    float* __restrict__ S_g, float* __restrict__ dtsum,
    float* __restrict__ out, float* __restrict__ xdbl)
{
    const int blk = blockIdx.x;
    const int k = blk >> 7;
    const int c = blk & 127;
    const int l0 = c * LC;
    const int t = threadIdx.x;

    __shared__ __align__(16) float xs[LC * XST];    // x-tile [l][d]; y overwrites
    __shared__ __align__(16) float sdbl[LC * SDST]; // x_dbl [l][c]
    __shared__ int pos_s[LC];

    if (t < LC) pos_s[t] = pos_of(k, l0 + t);
    __syncthreads();

    // ---- stage x tile: 4 passes x 8 rows x 32 lanes b128 (coalesced) ----
    {
        int lane32 = t & 31, rowi = t >> 5;
        #pragma unroll
        for (int p = 0; p < 4; p++) {
            int l = p * 8 + rowi;
            float4 v = *(const float4*)(x + (size_t)pos_s[l] * DD + lane32 * 4);
            *(float4*)(&xs[l * XST + lane32 * 4]) = v;
        }
    }
    __syncthreads();

    // ---- projection GEMM: group cg (of 8) computes 5 of 40 channels ----
    {
        int l = t & 31, cg = t >> 5;
        float acc[5];
        #pragma unroll
        for (int j = 0; j < 5; j++) acc[j] = 0.0f;
        const float* wk = Wp + (size_t)(k * 40 + cg * 5) * DD;
        for (int d4 = 0; d4 < DD; d4 += 4) {
            float4 xv = *(const float4*)(&xs[l * XST + d4]);
            #pragma unroll
            for (int j = 0; j < 5; j++) {
                const float* w = wk + j * DD + d4;   // wave-uniform -> s_load
                acc[j] += xv.x * w[0] + xv.y * w[1] + xv.z * w[2] + xv.w * w[3];
            }
        }
        #pragma unroll
        for (int j = 0; j < 5; j++) sdbl[l * SDST + cg * 5 + j] = acc[j];
    }
    __syncthreads();

    // ---- spill x_dbl tile for K3 ----
    {
        const float4* s4 = (const float4*)sdbl;
        float4* g4 = (float4*)(xdbl + (size_t)blk * XDBL_TILE);
        for (int idx = t; idx < XDBL_TILE / 4; idx += 256) g4[idx] = s4[idx];
    }

    // ---- phase A scan: thread = (d, n-half) ----
    const int d = t >> 1, half = t & 1, n0 = half * 8;
    float A8[8], A0;
    bool structured = load_A8(A_logs, k, d, n0, A8, A0);
    const float4* wp4 = (const float4*)(Wdt + (size_t)(k * DD + d) * RR);
    const float4 w0 = wp4[0], w1 = wp4[1];
    const float bz = bias[k * DD + d];
    const float Dval = Ds[k * DD + d];

    if (structured)
        scanA_body<true>(xs, sdbl, k, c, d, half, n0, A8, A0, w0, w1, bz,
                         Dval, S_g, dtsum);
    else
        scanA_body<false>(xs, sdbl, k, c, d, half, n0, A8, A0, w0, w1, bz,
                          Dval, S_g, dtsum);

    // ---- atomic merge: out[(p<<7) + (l&127)] += mw[k]*y  (16 consecutive) ----
    {
        float mwk = mw[k];
        int jb = (d << 5) | (c >> 2);
        int p = inv_pos(k, jb);
        float* obase = out + (p << 7) + ((c & 3) * 32) + half * 16;
        #pragma unroll
        for (int j = 0; j < 16; j++)
            atomicAdd(obase + j, mwk * xs[(half * 16 + j) * XST + d]);
    }
}

// ---------------------------------------------------------------------------
// K2: sequential combine across 128 chunks; S <- true h0, in place.
// ---------------------------------------------------------------------------
__global__ __launch_bounds__(256) void k2_combine(
    float* __restrict__ S_g, const float* __restrict__ dtsum,
    const float* __restrict__ A_logs)
{
    int tid = blockIdx.x * 256 + threadIdx.x;   // k*2048 + d*16 + n
    int kk = tid >> 11, rem = tid & 2047, dd2 = rem >> 4;
    float Ac = -__expf(A_logs[tid]);
    float hh = 0.0f;
    #pragma unroll 8
    for (int c2 = 0; c2 < NC; c2++) {
        size_t base = ((size_t)(kk * NC + c2)) * 2048 + rem;
        float s = S_g[base];
        float dsv = dtsum[(kk * NC + c2) * DD + dd2];
        S_g[base] = hh;
        hh = s + __expf(dsv * Ac) * hh;
    }
}

// ---------------------------------------------------------------------------
// K3 body: y(l) = C(l) . (exp(Dsum_l * A) (.) h0). Serial chain = 1 add.
// ---------------------------------------------------------------------------
template<bool S>
__device__ __forceinline__ void corr_body(
    float* ybuf, const float* sdbl, int d, int half, int n0,
    const float* A8, float A0, const float* h0, float4 w0, float4 w1, float bz)
{
    float Dsum = 0.0f;
    #pragma unroll 4
    for (int i = 0; i < LC; i++) {
        float z = delta_row_z(sdbl, i, w0, w1, bz);
        float E = __expf(-fabsf(z));
        float dt = fmaxf(z, 0.0f) + __logf(1.0f + E);
        Dsum += dt;
        float e[8];
        e8_from<S>(Dsum, A0, A8, half, e);
        const float4* cp = (const float4*)(&sdbl[i * SDST + 24 + n0]);
        float4 c0 = cp[0], c1 = cp[1];
        float yp = e[0]*h0[0]*c0.x + e[1]*h0[1]*c0.y + e[2]*h0[2]*c0.z + e[3]*h0[3]*c0.w
                 + e[4]*h0[4]*c1.x + e[5]*h0[5]*c1.y + e[6]*h0[6]*c1.z + e[7]*h0[7]*c1.w;
        float yv = yp + __shfl_xor(yp, 1);
        if (!half) ybuf[i * XST + d] = yv;
    }
}

__global__ __launch_bounds__(256, 4) void k3_corr(
    const float* __restrict__ Wdt, const float* __restrict__ bias,
    const float* __restrict__ A_logs, const float* __restrict__ S_g,
    const float* __restrict__ xdbl, const float* __restrict__ mw,
    float* __restrict__ out)
{
    const int blk = blockIdx.x;
    const int k = blk >> 7;
    const int c = blk & 127;
    if (c == 0) return;                 // chunk 0 has h0 = 0
    const int t = threadIdx.x;

    __shared__ __align__(16) float sdbl[LC * SDST];
    __shared__ __align__(16) float ybuf[LC * XST];
    {
        const float4* g4 = (const float4*)(xdbl + (size_t)blk * XDBL_TILE);
        float4* s4 = (float4*)sdbl;
        for (int idx = t; idx < XDBL_TILE / 4; idx += 256) s4[idx] = g4[idx];
    }
    __syncthreads();

    const int d = t >> 1, half = t & 1, n0 = half * 8;
    float A8[8], A0;
    bool structured = load_A8(A_logs, k, d, n0, A8, A0);
    const float4* wp4 = (const float4*)(Wdt + (size_t)(k * DD + d) * RR);
    const float4 w0 = wp4[0], w1 = wp4[1];
    const float bz = bias[k * DD + d];

    float h0[8];
    {
        const float4* hp = (const float4*)(S_g + (((size_t)(k * NC + c) * DD + d) * NN + n0));
        float4 h40 = hp[0], h41 = hp[1];
        h0[0] = h40.x; h0[1] = h40.y; h0[2] = h40.z; h0[3] = h40.w;
        h0[4] = h41.x; h0[5] = h41.y; h0[6] = h41.z; h0[7] = h41.w;
    }

    if (structured)
        corr_body<true>(ybuf, sdbl, d, half, n0, A8, A0, h0, w0, w1, bz);
    else
        corr_body<false>(ybuf, sdbl, d, half, n0, A8, A0, h0, w0, w1, bz);

    // ---- atomic merge of correction into out ----
    {
        float mwk = mw[k];
        int jb = (d << 5) | (c >> 2);
        int p = inv_pos(k, jb);
        float* obase = out + (p << 7) + ((c & 3) * 32) + half * 16;
        #pragma unroll
        for (int j = 0; j < 16; j++)
            atomicAdd(obase + j, mwk * ybuf[(half * 16 + j) * XST + d]);
    }
}

extern "C" void kernel_launch(void* const* d_in, const int* in_sizes, int n_in,
                              void* d_out, int out_size, void* d_ws, size_t ws_size,
                              hipStream_t stream) {
    const float* x      = (const float*)d_in[0];
    const float* Wp     = (const float*)d_in[1];
    const float* Wdt    = (const float*)d_in[2];
    const float* bias   = (const float*)d_in[3];
    const float* A_logs = (const float*)d_in[4];
    const float* Ds     = (const float*)d_in[5];
    const float* mw     = (const float*)d_in[6];
    const float* mb     = (const float*)d_in[7];
    float* out = (float*)d_out;

    float* ws   = (float*)d_ws;
    float* S_g  = ws;                                 // K*NC*D*N = 1572864
    float* dts  = S_g + (size_t)KK * NC * DD * NN;    // K*NC*D   =   98304
    float* xdbl = dts + (size_t)KK * NC * DD;         // 1536*1408 = 2162688

    k0_init<<<dim3(LL * DD / 4 / 256), dim3(256), 0, stream>>>(out, mb);
    k1_proj_scanA<<<dim3(KK * NC), dim3(256), 0, stream>>>(
        x, Wp, Wdt, bias, A_logs, Ds, mw, S_g, dts, out, xdbl);
    k2_combine<<<dim3(KK * DD * NN / 256), dim3(256), 0, stream>>>(S_g, dts, A_logs);
    k3_corr<<<dim3(KK * NC), dim3(256), 0, stream>>>(
        Wdt, bias, A_logs, S_g, xdbl, mw, out);
}

// Round 10
// 181.280 us; speedup vs baseline: 4.0546x; 4.0546x over previous
//
#include <hip/hip_runtime.h>

#define KK 12
#define LL 4096
#define DD 128
#define NN 16
#define RR 8
#define NC 256             // sub-chunks (two per block)
#define LCS 16             // sub-chunk length
#define LB 32              // block l-tile
#define XST 140            // x-tile / ybuf LDS stride (4-way GEMM reads)
#define SDST 44            // x_dbl LDS row stride (floats)
#define XDBL_TILE (LB * SDST)   // 1408 floats per (k, 32-l tile)

__device__ __forceinline__ int pos_of(int k, int l) {
    int o = k >> 1;
    int le = (k & 1) ? (4095 - l) : l;
    int t1 = le >> 8, t2 = (le >> 4) & 15, t3 = le & 15;
    switch (o) {
        case 0:  return (t1 << 8) | (t2 << 4) | t3;
        case 1:  return (t1 << 8) | (t3 << 4) | t2;
        case 2:  return (t3 << 8) | (t2 << 4) | t1;
        case 3:  return (t2 << 8) | (t3 << 4) | t1;
        case 4:  return (t2 << 8) | (t1 << 4) | t3;
        default: return (t3 << 8) | (t1 << 4) | t2;
    }
}

__device__ __forceinline__ float delta_row_z(const float* sdbl, int l,
                                             float4 w0, float4 w1, float bz) {
    const float4* dr = (const float4*)(sdbl + l * SDST);
    float4 r0 = dr[0], r1 = dr[1];
    return bz + w0.x * r0.x + w0.y * r0.y + w0.z * r0.z + w0.w * r0.w
              + w1.x * r1.x + w1.y * r1.y + w1.z * r1.z + w1.w * r1.w;
}

// Load -exp(A_logs[k][d][0..15]); check A[n] == (n+1)*A[0] structure.
__device__ __forceinline__ bool load_A16(const float* __restrict__ A_logs,
                                         int k, int d, float* A16) {
    const float4* ap = (const float4*)(A_logs + (size_t)(k * DD + d) * NN);
    #pragma unroll
    for (int q = 0; q < 4; q++) {
        float4 a4 = ap[q];
        A16[4*q+0] = -__expf(a4.x); A16[4*q+1] = -__expf(a4.y);
        A16[4*q+2] = -__expf(a4.z); A16[4*q+3] = -__expf(a4.w);
    }
    bool s = true;
    #pragma unroll
    for (int j = 1; j < 16; j++) {
        float m = (float)(j + 1);
        s = s && (fabsf(A16[j] - m * A16[0]) <= 1e-4f * m * fabsf(A16[0]));
    }
    return s;
}

// e[j] = q^(j+1) (structured, q given) or exp(v*A16[j]) (generic)
template<bool S>
__device__ __forceinline__ void e16_from(float v, float q, const float* A16,
                                         float* e) {
    if (S) {
        e[0] = q;
        #pragma unroll
        for (int j = 1; j < 16; j++) e[j] = e[j - 1] * q;
    } else {
        #pragma unroll
        for (int j = 0; j < 16; j++) e[j] = __expf(v * A16[j]);
    }
}

// ---------------------------------------------------------------------------
// K1 scan body. Thread = (d, l-half): all 16 states, 16 serial steps.
// Every sdbl read is wave-uniform; each (l,d) dt computed exactly once;
// y-dot completes in-thread. y overwrites the consumed xs slot (exclusive).
// ---------------------------------------------------------------------------
template<bool S>
__device__ __forceinline__ void scanA_body(
    float* xs, const float* sdbl, int k, int cc, int lbase, int d,
    const float* A16, float4 w0, float4 w1, float bz, float Dval,
    float* __restrict__ S_g, float* __restrict__ dtsum)
{
    float h[16];
    #pragma unroll
    for (int n = 0; n < 16; n++) h[n] = 0.0f;
    float dsum = 0.0f;

    #pragma unroll 4
    for (int i = 0; i < LCS; i++) {
        int l = lbase + i;
        float z = delta_row_z(sdbl, l, w0, w1, bz);
        float E = __expf(-fabsf(z));
        float dt = fmaxf(z, 0.0f) + __logf(1.0f + E);
        float u = xs[l * XST + d];
        dsum += dt;
        float tu = dt * u;
        float q = S ? __expf(dt * A16[0]) : 0.0f;
        float e[16];
        e16_from<S>(dt, q, A16, e);
        const float4* bp = (const float4*)(&sdbl[l * SDST + 8]);
        float4 b0 = bp[0], b1 = bp[1], b2 = bp[2], b3 = bp[3];
        const float4* cp = (const float4*)(&sdbl[l * SDST + 24]);
        float4 c0 = cp[0], c1 = cp[1], c2 = cp[2], c3 = cp[3];
        h[0]  = e[0]  * h[0]  + tu * b0.x;  h[1]  = e[1]  * h[1]  + tu * b0.y;
        h[2]  = e[2]  * h[2]  + tu * b0.z;  h[3]  = e[3]  * h[3]  + tu * b0.w;
        h[4]  = e[4]  * h[4]  + tu * b1.x;  h[5]  = e[5]  * h[5]  + tu * b1.y;
        h[6]  = e[6]  * h[6]  + tu * b1.z;  h[7]  = e[7]  * h[7]  + tu * b1.w;
        h[8]  = e[8]  * h[8]  + tu * b2.x;  h[9]  = e[9]  * h[9]  + tu * b2.y;
        h[10] = e[10] * h[10] + tu * b2.z;  h[11] = e[11] * h[11] + tu * b2.w;
        h[12] = e[12] * h[12] + tu * b3.x;  h[13] = e[13] * h[13] + tu * b3.y;
        h[14] = e[14] * h[14] + tu * b3.z;  h[15] = e[15] * h[15] + tu * b3.w;
        float y = h[0]*c0.x + h[1]*c0.y + h[2]*c0.z + h[3]*c0.w
                + h[4]*c1.x + h[5]*c1.y + h[6]*c1.z + h[7]*c1.w
                + h[8]*c2.x + h[9]*c2.y + h[10]*c2.z + h[11]*c2.w
                + h[12]*c3.x + h[13]*c3.y + h[14]*c3.z + h[15]*c3.w;
        xs[l * XST + d] = y + Dval * u;
    }

    float4* sp = (float4*)(S_g + (((size_t)(k * NC + cc) * DD + d) * NN));
    sp[0] = make_float4(h[0],  h[1],  h[2],  h[3]);
    sp[1] = make_float4(h[4],  h[5],  h[6],  h[7]);
    sp[2] = make_float4(h[8],  h[9],  h[10], h[11]);
    sp[3] = make_float4(h[12], h[13], h[14], h[15]);
    dtsum[(k * NC + cc) * DD + d] = dsum;
}

// ---------------------------------------------------------------------------
// K1: proj GEMM + phase A local scan. Block = (k, 32-l tile), 256 threads.
// LDS ~23.6 KB -> 6 blocks/CU (grid 1536 = exactly 6/CU).
// ---------------------------------------------------------------------------
__global__ __launch_bounds__(256, 4) void k1_proj_scanA(
    const float* __restrict__ x, const float* __restrict__ Wp,
    const float* __restrict__ Wdt, const float* __restrict__ bias,
    const float* __restrict__ A_logs, const float* __restrict__ Ds,
    float* __restrict__ S_g, float* __restrict__ dtsum,
    float* __restrict__ oy, float* __restrict__ xdbl)
{
    const int blk = blockIdx.x;
    const int k = blk >> 7;
    const int c = blk & 127;
    const int l0 = c * LB;
    const int t = threadIdx.x;

    __shared__ __align__(16) float xs[LB * XST];    // x-tile [l][d]; y overwrites
    __shared__ __align__(16) float sdbl[LB * SDST]; // x_dbl [l][c]
    __shared__ int pos_s[LB];

    if (t < LB) pos_s[t] = pos_of(k, l0 + t);
    __syncthreads();

    // ---- stage x tile: 4 passes x 8 rows x 32 lanes b128 (coalesced) ----
    {
        int lane32 = t & 31, rowi = t >> 5;
        #pragma unroll
        for (int p = 0; p < 4; p++) {
            int l = p * 8 + rowi;
            float4 v = *(const float4*)(x + (size_t)pos_s[l] * DD + lane32 * 4);
            *(float4*)(&xs[l * XST + lane32 * 4]) = v;
        }
    }
    __syncthreads();

    // ---- projection GEMM: group cg (of 8) computes 5 of 40 channels ----
    {
        int l = t & 31, cg = t >> 5;
        float acc[5];
        #pragma unroll
        for (int j = 0; j < 5; j++) acc[j] = 0.0f;
        const float* wk = Wp + (size_t)(k * 40 + cg * 5) * DD;
        for (int d4 = 0; d4 < DD; d4 += 4) {
            float4 xv = *(const float4*)(&xs[l * XST + d4]);
            #pragma unroll
            for (int j = 0; j < 5; j++) {
                const float* w = wk + j * DD + d4;   // wave-uniform -> s_load
                acc[j] += xv.x * w[0] + xv.y * w[1] + xv.z * w[2] + xv.w * w[3];
            }
        }
        #pragma unroll
        for (int j = 0; j < 5; j++) sdbl[l * SDST + cg * 5 + j] = acc[j];
    }
    __syncthreads();

    // ---- spill x_dbl tile for K3 ----
    {
        const float4* s4 = (const float4*)sdbl;
        float4* g4 = (float4*)(xdbl + (size_t)blk * XDBL_TILE);
        for (int idx = t; idx < XDBL_TILE / 4; idx += 256) g4[idx] = s4[idx];
    }

    // ---- phase A scan: thread = (d, l-half) ----
    const int d = t & 127, half = t >> 7;
    const int cc = 2 * c + half, lbase = half * LCS;
    float A16[16];
    bool structured = load_A16(A_logs, k, d, A16);
    const float4* wp4 = (const float4*)(Wdt + (size_t)(k * DD + d) * RR);
    const float4 w0 = wp4[0], w1 = wp4[1];
    const float bz = bias[k * DD + d];
    const float Dval = Ds[k * DD + d];

    if (structured)
        scanA_body<true>(xs, sdbl, k, cc, lbase, d, A16, w0, w1, bz, Dval,
                         S_g, dtsum);
    else
        scanA_body<false>(xs, sdbl, k, cc, lbase, d, A16, w0, w1, bz, Dval,
                          S_g, dtsum);

    // ---- transposed y store (self-written slots only; no barrier) ----
    {
        float* base = oy + ((size_t)(k * DD + d)) * LL + l0 + lbase;
        #pragma unroll
        for (int p = 0; p < 4; p++) {
            int j = p * 4;
            float4 v = make_float4(xs[(lbase + j + 0) * XST + d],
                                   xs[(lbase + j + 1) * XST + d],
                                   xs[(lbase + j + 2) * XST + d],
                                   xs[(lbase + j + 3) * XST + d]);
            *(float4*)(base + j) = v;
        }
    }
}

// ---------------------------------------------------------------------------
// K2: sequential combine across 256 sub-chunks; S <- true h0, in place.
// ---------------------------------------------------------------------------
__global__ __launch_bounds__(256) void k2_combine(
    float* __restrict__ S_g, const float* __restrict__ dtsum,
    const float* __restrict__ A_logs)
{
    int tid = blockIdx.x * 256 + threadIdx.x;   // k*2048 + d*16 + n
    int kk = tid >> 11, rem = tid & 2047, dd2 = rem >> 4;
    float Ac = -__expf(A_logs[tid]);
    float hh = 0.0f;
    #pragma unroll 8
    for (int c2 = 0; c2 < NC; c2++) {
        size_t base = ((size_t)(kk * NC + c2)) * 2048 + rem;
        float s = S_g[base];
        float dsv = dtsum[(kk * NC + c2) * DD + dd2];
        S_g[base] = hh;
        hh = s + __expf(dsv * Ac) * hh;
    }
}

// ---------------------------------------------------------------------------
// K3 body: y(l) = C(l) . (P_l (.) h0), P_l = prod_{i<=l} exp(dt_i * A).
// Structured: P *= exp(dt*A0) (1 exp), e_j = P^(j+1) (15 muls) - no other
// transcendentals. Generic fallback: per-step exps of Dsum*A.
// ---------------------------------------------------------------------------
template<bool S>
__device__ __forceinline__ void corr_body(
    float* ybuf, const float* sdbl, int lbase, int d,
    const float* A16, const float* h0, float4 w0, float4 w1, float bz)
{
    float P = 1.0f;     // structured: running product of exp(dt*A0)
    float Dsum = 0.0f;  // generic: running sum of dt
    #pragma unroll 4
    for (int i = 0; i < LCS; i++) {
        int l = lbase + i;
        float z = delta_row_z(sdbl, l, w0, w1, bz);
        float E = __expf(-fabsf(z));
        float dt = fmaxf(z, 0.0f) + __logf(1.0f + E);
        float e[16];
        if (S) {
            P *= __expf(dt * A16[0]);
            e16_from<true>(0.0f, P, A16, e);
        } else {
            Dsum += dt;
            e16_from<false>(Dsum, 0.0f, A16, e);
        }
        const float4* cp = (const float4*)(&sdbl[l * SDST + 24]);
        float4 c0 = cp[0], c1 = cp[1], c2 = cp[2], c3 = cp[3];
        float y = e[0]*h0[0]*c0.x + e[1]*h0[1]*c0.y + e[2]*h0[2]*c0.z + e[3]*h0[3]*c0.w
                + e[4]*h0[4]*c1.x + e[5]*h0[5]*c1.y + e[6]*h0[6]*c1.z + e[7]*h0[7]*c1.w
                + e[8]*h0[8]*c2.x + e[9]*h0[9]*c2.y + e[10]*h0[10]*c2.z + e[11]*h0[11]*c2.w
                + e[12]*h0[12]*c3.x + e[13]*h0[13]*c3.y + e[14]*h0[14]*c3.z + e[15]*h0[15]*c3.w;
        ybuf[l * XST + d] = y;
    }
}

__global__ __launch_bounds__(256, 4) void k3_corr(
    const float* __restrict__ Wdt, const float* __restrict__ bias,
    const float* __restrict__ A_logs, const float* __restrict__ S_g,
    const float* __restrict__ xdbl, float* __restrict__ oy)
{
    const int blk = blockIdx.x;
    const int k = blk >> 7;
    const int c = blk & 127;
    const int l0 = c * LB;
    const int t = threadIdx.x;

    __shared__ __align__(16) float sdbl[LB * SDST];
    __shared__ __align__(16) float ybuf[LB * XST];
    {
        const float4* g4 = (const float4*)(xdbl + (size_t)blk * XDBL_TILE);
        float4* s4 = (float4*)sdbl;
        for (int idx = t; idx < XDBL_TILE / 4; idx += 256) s4[idx] = g4[idx];
    }
    __syncthreads();

    const int d = t & 127, half = t >> 7;
    const int cc = 2 * c + half, lbase = half * LCS;
    float A16[16];
    bool structured = load_A16(A_logs, k, d, A16);
    const float4* wp4 = (const float4*)(Wdt + (size_t)(k * DD + d) * RR);
    const float4 w0 = wp4[0], w1 = wp4[1];
    const float bz = bias[k * DD + d];

    float h0[16];
    {
        const float4* hp = (const float4*)(S_g + (((size_t)(k * NC + cc) * DD + d) * NN));
        float4 a = hp[0], b = hp[1], c4 = hp[2], e4 = hp[3];
        h0[0]  = a.x;  h0[1]  = a.y;  h0[2]  = a.z;  h0[3]  = a.w;
        h0[4]  = b.x;  h0[5]  = b.y;  h0[6]  = b.z;  h0[7]  = b.w;
        h0[8]  = c4.x; h0[9]  = c4.y; h0[10] = c4.z; h0[11] = c4.w;
        h0[12] = e4.x; h0[13] = e4.y; h0[14] = e4.z; h0[15] = e4.w;
    }

    if (structured)
        corr_body<true>(ybuf, sdbl, lbase, d, A16, h0, w0, w1, bz);
    else
        corr_body<false>(ybuf, sdbl, lbase, d, A16, h0, w0, w1, bz);

    // ---- transposed RMW of oy tile (self-written slots only) ----
    {
        float* base = oy + ((size_t)(k * DD + d)) * LL + l0 + lbase;
        #pragma unroll
        for (int p = 0; p < 4; p++) {
            int j = p * 4;
            float4 v = *(float4*)(base + j);
            v.x += ybuf[(lbase + j + 0) * XST + d];
            v.y += ybuf[(lbase + j + 1) * XST + d];
            v.z += ybuf[(lbase + j + 2) * XST + d];
            v.w += ybuf[(lbase + j + 3) * XST + d];
            *(float4*)(base + j) = v;
        }
    }
}

// ---------------------------------------------------------------------------
// K4: restore + merge (reference's (D,L)-flat reshape semantics).
// ---------------------------------------------------------------------------
__global__ __launch_bounds__(256) void k4_merge(
    const float* __restrict__ out_y, const float* __restrict__ mw,
    const float* __restrict__ mb, float* __restrict__ out)
{
    int idx = blockIdx.x * 256 + threadIdx.x;
    int dd = idx & 127;
    int p = idx >> 7;
    int i3 = p & 15, i2 = (p >> 4) & 15, i1 = (p >> 8) & 15;

    float accv = mb[0];
    #pragma unroll
    for (int k = 0; k < 12; k++) {
        int a1 = i1, a2 = i2, a3 = i3;
        if (k & 1) { a1 = 15 - i1; a2 = 15 - i2; a3 = 15 - i3; }
        int j1, j2, j3;
        switch (k >> 1) {
            case 0:  j1 = a1; j2 = a2; j3 = a3; break;
            case 1:  j1 = a1; j2 = a3; j3 = a2; break;
            case 2:  j1 = a3; j2 = a2; j3 = a1; break;
            case 3:  j1 = a3; j2 = a1; j3 = a2; break;
            case 4:  j1 = a2; j2 = a1; j3 = a3; break;
            default: j1 = a2; j2 = a3; j3 = a1; break;
        }
        int jb = (j1 << 8) | (j2 << 4) | j3;
        accv += mw[k] * out_y[(size_t)k * (DD * LL) + (jb >> 5) * LL
                              + ((jb & 31) << 7) + dd];
    }
    out[idx] = accv;
}

extern "C" void kernel_launch(void* const* d_in, const int* in_sizes, int n_in,
                              void* d_out, int out_size, void* d_ws, size_t ws_size,
                              hipStream_t stream) {
    const float* x      = (const float*)d_in[0];
    const float* Wp     = (const float*)d_in[1];
    const float* Wdt    = (const float*)d_in[2];
    const float* bias   = (const float*)d_in[3];
    const float* A_logs = (const float*)d_in[4];
    const float* Ds     = (const float*)d_in[5];
    const float* mw     = (const float*)d_in[6];
    const float* mb     = (const float*)d_in[7];
    float* out = (float*)d_out;

    float* ws   = (float*)d_ws;
    float* S_g  = ws;                                 // K*NC*D*N = 6291456
    float* dts  = S_g + (size_t)KK * NC * DD * NN;    // K*NC*D   =  393216
    float* oy   = dts + (size_t)KK * NC * DD;         // K*D*L    = 6291456
    float* xdbl = oy + (size_t)KK * DD * LL;          // 1536*1408 = 2162688

    k1_proj_scanA<<<dim3(KK * 128), dim3(256), 0, stream>>>(
        x, Wp, Wdt, bias, A_logs, Ds, S_g, dts, oy, xdbl);
    k2_combine<<<dim3(KK * DD * NN / 256), dim3(256), 0, stream>>>(S_g, dts, A_logs);
    k3_corr<<<dim3(KK * 128), dim3(256), 0, stream>>>(
        Wdt, bias, A_logs, S_g, xdbl, oy);
    k4_merge<<<dim3(LL * DD / 256), dim3(256), 0, stream>>>(oy, mw, mb, out);
}